// Round 4
// baseline (238.377 us; speedup 1.0000x reference)
//
#include <hip/hip_runtime.h>
#include <math.h>

#define F_DIM 128
#define D_LAT 64
#define H_DIM 128

typedef __attribute__((ext_vector_type(8))) short bf16x8;        // 8 bf16 (4 VGPRs)
typedef __attribute__((ext_vector_type(8))) _Float16 f16x8;      // 8 fp16 (4 VGPRs)
typedef __attribute__((ext_vector_type(4))) float f32x4;

__device__ __forceinline__ unsigned short f2bf(float f) {
    unsigned int u = __builtin_bit_cast(unsigned int, f);
    return (unsigned short)((u + 0x8000u) >> 16);
}

// ---------------- encoder via MFMA: 16 nodes/wave, z stored fp16 ----------------
// mfma_f32_16x16x32_bf16 layouts (m89-verified, validated here by absmax 0.0):
//   A: lane l, elem j -> A[l&15][(l>>4)*8 + j]
//   B: lane l, elem j -> B[(l>>4)*8 + j][l&15]
//   D: lane l, reg r  -> D[(l>>4)*4 + r][l&15]
__global__ __launch_bounds__(256) void enc_mfma_kernel(
    const float* __restrict__ x, const float* __restrict__ eps,
    const float* __restrict__ Wmu, const float* __restrict__ bmu,
    const float* __restrict__ Wlv, const float* __restrict__ blv,
    _Float16* __restrict__ zh, float* __restrict__ accum, int nNodes)
{
    const int lane = threadIdx.x & 63;
    const int li   = lane & 15;
    const int gi   = lane >> 4;

    // register-resident weights: tiles 0..3 = Wmu cols, 4..7 = Wlv cols
    bf16x8 wf[8][4];
#pragma unroll
    for (int t = 0; t < 4; ++t)
#pragma unroll
        for (int s = 0; s < 4; ++s)
#pragma unroll
            for (int j = 0; j < 8; ++j) {
                const int k = s * 32 + gi * 8 + j;
                wf[t][s][j]     = (short)f2bf(Wmu[k * D_LAT + 16 * t + li]);
                wf[t + 4][s][j] = (short)f2bf(Wlv[k * D_LAT + 16 * t + li]);
            }
    float bmu4[4], blv4[4];
#pragma unroll
    for (int t = 0; t < 4; ++t) {
        bmu4[t] = bmu[16 * t + li];
        blv4[t] = blv[16 * t + li];
    }

    const int wid = (blockIdx.x * blockDim.x + threadIdx.x) >> 6;
    const int nw  = (gridDim.x * blockDim.x) >> 6;
    const int NB  = nNodes >> 4;

    float klacc = 0.f;
    for (int nb = wid; nb < NB; nb += nw) {
        const int nbase = nb << 4;
        const float* __restrict__ xrow = x + (size_t)(nbase + li) * F_DIM;

        bf16x8 af[4];
#pragma unroll
        for (int s = 0; s < 4; ++s) {
            const f32x4 v0 = *(const f32x4*)(xrow + s * 32 + gi * 8);
            const f32x4 v1 = *(const f32x4*)(xrow + s * 32 + gi * 8 + 4);
#pragma unroll
            for (int j = 0; j < 4; ++j) {
                af[s][j]     = (short)f2bf(v0[j]);
                af[s][j + 4] = (short)f2bf(v1[j]);
            }
        }

        // bias folded into accumulator init (col-only dependence)
        f32x4 acc[8];
#pragma unroll
        for (int t = 0; t < 4; ++t) {
            acc[t]     = (f32x4){bmu4[t], bmu4[t], bmu4[t], bmu4[t]};
            acc[t + 4] = (f32x4){blv4[t], blv4[t], blv4[t], blv4[t]};
        }
#pragma unroll
        for (int t = 0; t < 8; ++t)
#pragma unroll
            for (int s = 0; s < 4; ++s)
                acc[t] = __builtin_amdgcn_mfma_f32_16x16x32_bf16(af[s], wf[t][s], acc[t], 0, 0, 0);

#pragma unroll
        for (int r = 0; r < 4; ++r) {
            const int row = nbase + gi * 4 + r;
#pragma unroll
            for (int t = 0; t < 4; ++t) {
                const float mu  = acc[t][r];
                const float lv  = acc[t + 4][r];
                const float e05 = __expf(0.5f * lv);
                klacc += mu * mu + e05 * e05 - 1.0f - lv;
                const float zv = fmaf(eps[(size_t)row * D_LAT + 16 * t + li], e05, mu);
                zh[(size_t)row * D_LAT + 16 * t + li] = (_Float16)zv;
            }
        }
    }
    for (int off = 32; off; off >>= 1) klacc += __shfl_xor(klacc, off);
    if (lane == 0) atomicAdd(&accum[1], 0.5f * klacc);
}

// ---------------- edge scorer: 16 pairs/wave, fp16 MFMA ----------------
__global__ __launch_bounds__(256) void edge_mfma_kernel(
    const _Float16* __restrict__ zh,
    const int* __restrict__ eidx, const int* __restrict__ nidx,
    const float* __restrict__ W1, const float* __restrict__ b1,
    const float* __restrict__ W2, const float* __restrict__ b2,
    float* __restrict__ accum, int E)
{
    const int lane = threadIdx.x & 63;
    const int li   = lane & 15;
    const int gi   = lane >> 4;

    f16x8 w1f[8][2];
#pragma unroll
    for (int t = 0; t < 8; ++t)
#pragma unroll
        for (int s = 0; s < 2; ++s)
#pragma unroll
            for (int j = 0; j < 8; ++j)
                w1f[t][s][j] = (_Float16)W1[(32 * s + gi * 8 + j) * H_DIM + 16 * t + li];
    float b1r[8], w2r[8];
#pragma unroll
    for (int t = 0; t < 8; ++t) {
        b1r[t] = b1[16 * t + li];
        w2r[t] = W2[16 * t + li];
    }
    const float b2v = b2[0];

    const int wid = (blockIdx.x * blockDim.x + threadIdx.x) >> 6;
    const int nw  = (gridDim.x * blockDim.x) >> 6;
    const int NBpos = E >> 4;
    const int NB    = NBpos << 1;

    float lp = 0.f;
    for (int pb = wid; pb < NB; pb += nw) {
        const bool pos = pb < NBpos;
        const int pbase = (pos ? pb : pb - NBpos) << 4;
        const int* __restrict__ idx = pos ? eidx : nidx;
        const int u = idx[pbase + li];
        const int v = idx[E + pbase + li];

        const _Float16* zu = zh + (size_t)u * D_LAT + gi * 8;
        const _Float16* zv = zh + (size_t)v * D_LAT + gi * 8;
        const f16x8 a0 = *(const f16x8*)(zu);
        const f16x8 a1 = *(const f16x8*)(zu + 32);
        const f16x8 c0 = *(const f16x8*)(zv);
        const f16x8 c1 = *(const f16x8*)(zv + 32);

        const f16x8 pa0 = a0 * c0;   // v_pk_mul_f16
        const f16x8 pa1 = a1 * c1;

        // bias folded into acc init
        f32x4 acc[8];
#pragma unroll
        for (int t = 0; t < 8; ++t)
            acc[t] = (f32x4){b1r[t], b1r[t], b1r[t], b1r[t]};
#pragma unroll
        for (int t = 0; t < 8; ++t) {
            acc[t] = __builtin_amdgcn_mfma_f32_16x16x32_f16(pa0, w1f[t][0], acc[t], 0, 0, 0);
            acc[t] = __builtin_amdgcn_mfma_f32_16x16x32_f16(pa1, w1f[t][1], acc[t], 0, 0, 0);
        }

        float t0 = 0.f, t1 = 0.f, t2 = 0.f, t3 = 0.f;
#pragma unroll
        for (int t = 0; t < 8; ++t) {
            t0 += fmaxf(acc[t][0], 0.f) * w2r[t];
            t1 += fmaxf(acc[t][1], 0.f) * w2r[t];
            t2 += fmaxf(acc[t][2], 0.f) * w2r[t];
            t3 += fmaxf(acc[t][3], 0.f) * w2r[t];
        }
#pragma unroll
        for (int off = 1; off < 16; off <<= 1) {
            t0 += __shfl_xor(t0, off);
            t1 += __shfl_xor(t1, off);
            t2 += __shfl_xor(t2, off);
            t3 += __shfl_xor(t3, off);
        }
        const float sg = pos ? 1.f : -1.f;
        const float l0 = sg * (t0 + b2v), l1 = sg * (t1 + b2v);
        const float l2 = sg * (t2 + b2v), l3 = sg * (t3 + b2v);
        lp += fminf(l0, 0.f) - __logf(1.f + __expf(-fabsf(l0)));
        lp += fminf(l1, 0.f) - __logf(1.f + __expf(-fabsf(l1)));
        lp += fminf(l2, 0.f) - __logf(1.f + __expf(-fabsf(l2)));
        lp += fminf(l3, 0.f) - __logf(1.f + __expf(-fabsf(l3)));
    }
    for (int off = 32; off; off >>= 1) lp += __shfl_xor(lp, off);
    if (lane == 0) atomicAdd(&accum[0], lp * 0.0625f);
}

// ---------------- finalize ----------------
__global__ void fin_kernel(const float* __restrict__ accum, float* __restrict__ out,
                           int nNodes, int E)
{
    const float recon = accum[0] / (float)(2 * E);
    const float kl    = accum[1] / (float)nNodes;
    out[0] = kl - recon;
}

extern "C" void kernel_launch(void* const* d_in, const int* in_sizes, int n_in,
                              void* d_out, int out_size, void* d_ws, size_t ws_size,
                              hipStream_t stream)
{
    const float* x    = (const float*)d_in[0];
    const float* eps  = (const float*)d_in[1];
    const float* Wmu  = (const float*)d_in[2];
    const float* bmu  = (const float*)d_in[3];
    const float* Wlv  = (const float*)d_in[4];
    const float* blv  = (const float*)d_in[5];
    const float* W1   = (const float*)d_in[6];
    const float* b1   = (const float*)d_in[7];
    const float* W2   = (const float*)d_in[8];
    const float* b2   = (const float*)d_in[9];
    const int*   eidx = (const int*)d_in[10];
    const int*   nidx = (const int*)d_in[11];

    const int nNodes = in_sizes[1] / D_LAT;   // 100000
    const int E      = in_sizes[10] / 2;      // 1000000

    float* accum  = (float*)d_ws;
    _Float16* zh  = (_Float16*)((char*)d_ws + 256);

    hipMemsetAsync(d_ws, 0, 256, stream);
    enc_mfma_kernel<<<512, 256, 0, stream>>>(x, eps, Wmu, bmu, Wlv, blv, zh, accum, nNodes);
    edge_mfma_kernel<<<2048, 256, 0, stream>>>(zh, eidx, nidx, W1, b1, W2, b2, accum, E);
    fin_kernel<<<1, 1, 0, stream>>>(accum, (float*)d_out, nNodes, E);
}

// Round 5
// 220.767 us; speedup vs baseline: 1.0798x; 1.0798x over previous
//
#include <hip/hip_runtime.h>
#include <math.h>

#define F_DIM 128
#define D_LAT 64
#define H_DIM 128

typedef __attribute__((ext_vector_type(8))) short bf16x8;        // 8 bf16 (4 VGPRs)
typedef __attribute__((ext_vector_type(8))) _Float16 f16x8;      // 8 fp16 (4 VGPRs)
typedef __attribute__((ext_vector_type(4))) float f32x4;

__device__ __forceinline__ unsigned short f2bf(float f) {
    unsigned int u = __builtin_bit_cast(unsigned int, f);
    return (unsigned short)((u + 0x8000u) >> 16);
}

// ---------------- encoder via MFMA: 16 nodes/wave, z stored fp16 ----------------
// mfma 16x16x32 layouts (m89-verified, validated by absmax 0.0 in R2/R3):
//   A: lane l, elem j -> A[l&15][(l>>4)*8 + j]
//   B: lane l, elem j -> B[(l>>4)*8 + j][l&15]
//   D: lane l, reg r  -> D[(l>>4)*4 + r][l&15]
__global__ __launch_bounds__(256) void enc_mfma_kernel(
    const float* __restrict__ x, const float* __restrict__ eps,
    const float* __restrict__ Wmu, const float* __restrict__ bmu,
    const float* __restrict__ Wlv, const float* __restrict__ blv,
    _Float16* __restrict__ zh, float* __restrict__ accum, int nNodes)
{
    const int lane = threadIdx.x & 63;
    const int li   = lane & 15;
    const int gi   = lane >> 4;

    bf16x8 wf[8][4];
#pragma unroll
    for (int t = 0; t < 4; ++t)
#pragma unroll
        for (int s = 0; s < 4; ++s)
#pragma unroll
            for (int j = 0; j < 8; ++j) {
                const int k = s * 32 + gi * 8 + j;
                wf[t][s][j]     = (short)f2bf(Wmu[k * D_LAT + 16 * t + li]);
                wf[t + 4][s][j] = (short)f2bf(Wlv[k * D_LAT + 16 * t + li]);
            }
    float bmu4[4], blv4[4];
#pragma unroll
    for (int t = 0; t < 4; ++t) {
        bmu4[t] = bmu[16 * t + li];
        blv4[t] = blv[16 * t + li];
    }

    const int wid = (blockIdx.x * blockDim.x + threadIdx.x) >> 6;
    const int nw  = (gridDim.x * blockDim.x) >> 6;
    const int NB  = nNodes >> 4;

    float klacc = 0.f;
    for (int nb = wid; nb < NB; nb += nw) {
        const int nbase = nb << 4;
        const float* __restrict__ xrow = x + (size_t)(nbase + li) * F_DIM;

        bf16x8 af[4];
#pragma unroll
        for (int s = 0; s < 4; ++s) {
            const f32x4 v0 = *(const f32x4*)(xrow + s * 32 + gi * 8);
            const f32x4 v1 = *(const f32x4*)(xrow + s * 32 + gi * 8 + 4);
#pragma unroll
            for (int j = 0; j < 4; ++j) {
                af[s][j]     = (short)f2bf(v0[j]);
                af[s][j + 4] = (short)f2bf(v1[j]);
            }
        }

        f32x4 acc[8];
#pragma unroll
        for (int t = 0; t < 4; ++t) {
            acc[t]     = (f32x4){bmu4[t], bmu4[t], bmu4[t], bmu4[t]};
            acc[t + 4] = (f32x4){blv4[t], blv4[t], blv4[t], blv4[t]};
        }
#pragma unroll
        for (int t = 0; t < 8; ++t)
#pragma unroll
            for (int s = 0; s < 4; ++s)
                acc[t] = __builtin_amdgcn_mfma_f32_16x16x32_bf16(af[s], wf[t][s], acc[t], 0, 0, 0);

#pragma unroll
        for (int r = 0; r < 4; ++r) {
            const int row = nbase + gi * 4 + r;
#pragma unroll
            for (int t = 0; t < 4; ++t) {
                const float mu  = acc[t][r];
                const float lv  = acc[t + 4][r];
                const float e05 = __expf(0.5f * lv);
                klacc += mu * mu + e05 * e05 - 1.0f - lv;
                const float zv = fmaf(eps[(size_t)row * D_LAT + 16 * t + li], e05, mu);
                zh[(size_t)row * D_LAT + 16 * t + li] = (_Float16)zv;
            }
        }
    }
    for (int off = 32; off; off >>= 1) klacc += __shfl_xor(klacc, off);
    if (lane == 0) atomicAdd(&accum[1], 0.5f * klacc);
}

// ---------------- edge scorer: 32 pairs/wave/iter, idx prefetched ----------------
__global__ __launch_bounds__(256) void edge_mfma_kernel(
    const _Float16* __restrict__ zh,
    const int* __restrict__ eidx, const int* __restrict__ nidx,
    const float* __restrict__ W1, const float* __restrict__ b1,
    const float* __restrict__ W2, const float* __restrict__ b2,
    float* __restrict__ accum, int E)
{
    const int lane = threadIdx.x & 63;
    const int li   = lane & 15;
    const int gi   = lane >> 4;

    f16x8 w1f[8][2];
#pragma unroll
    for (int t = 0; t < 8; ++t)
#pragma unroll
        for (int s = 0; s < 2; ++s)
#pragma unroll
            for (int j = 0; j < 8; ++j)
                w1f[t][s][j] = (_Float16)W1[(32 * s + gi * 8 + j) * H_DIM + 16 * t + li];
    float b1r[8], w2r[8];
#pragma unroll
    for (int t = 0; t < 8; ++t) {
        b1r[t] = b1[16 * t + li];
        w2r[t] = W2[16 * t + li];
    }
    const float b2v = b2[0];

    const int wid = (blockIdx.x * blockDim.x + threadIdx.x) >> 6;
    const int nw  = (gridDim.x * blockDim.x) >> 6;
    const int NBpos = E >> 4;         // 62500
    const int NB    = NBpos << 1;     // 125000 (even)
    const int NBH   = NB >> 1;        // 62500 half-iterations of 2 blocks

    float lp = 0.f;

    // prefetched indices for current hb (clamped so idle waves stay safe)
    int cu0, cv0, cu1, cv1;
    {
        const int hb  = (wid < NBH) ? wid : (NBH - 1);
        const int pb0 = 2 * hb, pb1 = 2 * hb + 1;
        const int* __restrict__ i0 = (pb0 < NBpos) ? eidx : nidx;
        const int* __restrict__ i1 = (pb1 < NBpos) ? eidx : nidx;
        const int m0 = ((pb0 < NBpos) ? pb0 : pb0 - NBpos) << 4;
        const int m1 = ((pb1 < NBpos) ? pb1 : pb1 - NBpos) << 4;
        cu0 = i0[m0 + li]; cv0 = i0[E + m0 + li];
        cu1 = i1[m1 + li]; cv1 = i1[E + m1 + li];
    }

    for (int hb = wid; hb < NBH; hb += nw) {
        const int pb0 = 2 * hb, pb1 = 2 * hb + 1;

        // --- issue all 8 z-row gathers for both blocks (idx already in regs) ---
        const _Float16* zu0 = zh + (size_t)cu0 * D_LAT + gi * 8;
        const _Float16* zv0 = zh + (size_t)cv0 * D_LAT + gi * 8;
        const _Float16* zu1 = zh + (size_t)cu1 * D_LAT + gi * 8;
        const _Float16* zv1 = zh + (size_t)cv1 * D_LAT + gi * 8;
        const f16x8 a00 = *(const f16x8*)(zu0);
        const f16x8 a01 = *(const f16x8*)(zu0 + 32);
        const f16x8 c00 = *(const f16x8*)(zv0);
        const f16x8 c01 = *(const f16x8*)(zv0 + 32);
        const f16x8 a10 = *(const f16x8*)(zu1);
        const f16x8 a11 = *(const f16x8*)(zu1 + 32);
        const f16x8 c10 = *(const f16x8*)(zv1);
        const f16x8 c11 = *(const f16x8*)(zv1 + 32);

        // --- prefetch indices for next iteration ---
        int nu0, nv0, nu1, nv1;
        {
            const int hn  = (hb + nw < NBH) ? hb + nw : hb;
            const int qb0 = 2 * hn, qb1 = 2 * hn + 1;
            const int* __restrict__ i0 = (qb0 < NBpos) ? eidx : nidx;
            const int* __restrict__ i1 = (qb1 < NBpos) ? eidx : nidx;
            const int m0 = ((qb0 < NBpos) ? qb0 : qb0 - NBpos) << 4;
            const int m1 = ((qb1 < NBpos) ? qb1 : qb1 - NBpos) << 4;
            nu0 = i0[m0 + li]; nv0 = i0[E + m0 + li];
            nu1 = i1[m1 + li]; nv1 = i1[E + m1 + li];
        }

        // --- compute block 0 ---
        {
            const f16x8 pa0 = a00 * c00;
            const f16x8 pa1 = a01 * c01;
            f32x4 acc[8];
#pragma unroll
            for (int t = 0; t < 8; ++t)
                acc[t] = (f32x4){b1r[t], b1r[t], b1r[t], b1r[t]};
#pragma unroll
            for (int t = 0; t < 8; ++t) {
                acc[t] = __builtin_amdgcn_mfma_f32_16x16x32_f16(pa0, w1f[t][0], acc[t], 0, 0, 0);
                acc[t] = __builtin_amdgcn_mfma_f32_16x16x32_f16(pa1, w1f[t][1], acc[t], 0, 0, 0);
            }
            float t0 = 0.f, t1 = 0.f, t2 = 0.f, t3 = 0.f;
#pragma unroll
            for (int t = 0; t < 8; ++t) {
                t0 += fmaxf(acc[t][0], 0.f) * w2r[t];
                t1 += fmaxf(acc[t][1], 0.f) * w2r[t];
                t2 += fmaxf(acc[t][2], 0.f) * w2r[t];
                t3 += fmaxf(acc[t][3], 0.f) * w2r[t];
            }
#pragma unroll
            for (int off = 1; off < 16; off <<= 1) {
                t0 += __shfl_xor(t0, off);
                t1 += __shfl_xor(t1, off);
                t2 += __shfl_xor(t2, off);
                t3 += __shfl_xor(t3, off);
            }
            const float sg = (pb0 < NBpos) ? 1.f : -1.f;
            const float l0 = sg * (t0 + b2v), l1 = sg * (t1 + b2v);
            const float l2 = sg * (t2 + b2v), l3 = sg * (t3 + b2v);
            lp += fminf(l0, 0.f) - __logf(1.f + __expf(-fabsf(l0)));
            lp += fminf(l1, 0.f) - __logf(1.f + __expf(-fabsf(l1)));
            lp += fminf(l2, 0.f) - __logf(1.f + __expf(-fabsf(l2)));
            lp += fminf(l3, 0.f) - __logf(1.f + __expf(-fabsf(l3)));
        }
        // --- compute block 1 ---
        {
            const f16x8 pa0 = a10 * c10;
            const f16x8 pa1 = a11 * c11;
            f32x4 acc[8];
#pragma unroll
            for (int t = 0; t < 8; ++t)
                acc[t] = (f32x4){b1r[t], b1r[t], b1r[t], b1r[t]};
#pragma unroll
            for (int t = 0; t < 8; ++t) {
                acc[t] = __builtin_amdgcn_mfma_f32_16x16x32_f16(pa0, w1f[t][0], acc[t], 0, 0, 0);
                acc[t] = __builtin_amdgcn_mfma_f32_16x16x32_f16(pa1, w1f[t][1], acc[t], 0, 0, 0);
            }
            float t0 = 0.f, t1 = 0.f, t2 = 0.f, t3 = 0.f;
#pragma unroll
            for (int t = 0; t < 8; ++t) {
                t0 += fmaxf(acc[t][0], 0.f) * w2r[t];
                t1 += fmaxf(acc[t][1], 0.f) * w2r[t];
                t2 += fmaxf(acc[t][2], 0.f) * w2r[t];
                t3 += fmaxf(acc[t][3], 0.f) * w2r[t];
            }
#pragma unroll
            for (int off = 1; off < 16; off <<= 1) {
                t0 += __shfl_xor(t0, off);
                t1 += __shfl_xor(t1, off);
                t2 += __shfl_xor(t2, off);
                t3 += __shfl_xor(t3, off);
            }
            const float sg = (pb1 < NBpos) ? 1.f : -1.f;
            const float l0 = sg * (t0 + b2v), l1 = sg * (t1 + b2v);
            const float l2 = sg * (t2 + b2v), l3 = sg * (t3 + b2v);
            lp += fminf(l0, 0.f) - __logf(1.f + __expf(-fabsf(l0)));
            lp += fminf(l1, 0.f) - __logf(1.f + __expf(-fabsf(l1)));
            lp += fminf(l2, 0.f) - __logf(1.f + __expf(-fabsf(l2)));
            lp += fminf(l3, 0.f) - __logf(1.f + __expf(-fabsf(l3)));
        }

        cu0 = nu0; cv0 = nv0; cu1 = nu1; cv1 = nv1;
    }
    for (int off = 32; off; off >>= 1) lp += __shfl_xor(lp, off);
    if (lane == 0) atomicAdd(&accum[0], lp * 0.0625f);
}

// ---------------- finalize ----------------
__global__ void fin_kernel(const float* __restrict__ accum, float* __restrict__ out,
                           int nNodes, int E)
{
    const float recon = accum[0] / (float)(2 * E);
    const float kl    = accum[1] / (float)nNodes;
    out[0] = kl - recon;
}

extern "C" void kernel_launch(void* const* d_in, const int* in_sizes, int n_in,
                              void* d_out, int out_size, void* d_ws, size_t ws_size,
                              hipStream_t stream)
{
    const float* x    = (const float*)d_in[0];
    const float* eps  = (const float*)d_in[1];
    const float* Wmu  = (const float*)d_in[2];
    const float* bmu  = (const float*)d_in[3];
    const float* Wlv  = (const float*)d_in[4];
    const float* blv  = (const float*)d_in[5];
    const float* W1   = (const float*)d_in[6];
    const float* b1   = (const float*)d_in[7];
    const float* W2   = (const float*)d_in[8];
    const float* b2   = (const float*)d_in[9];
    const int*   eidx = (const int*)d_in[10];
    const int*   nidx = (const int*)d_in[11];

    const int nNodes = in_sizes[1] / D_LAT;   // 100000
    const int E      = in_sizes[10] / 2;      // 1000000

    float* accum  = (float*)d_ws;
    _Float16* zh  = (_Float16*)((char*)d_ws + 256);

    hipMemsetAsync(d_ws, 0, 256, stream);
    enc_mfma_kernel<<<512, 256, 0, stream>>>(x, eps, Wmu, bmu, Wlv, blv, zh, accum, nNodes);
    edge_mfma_kernel<<<2048, 256, 0, stream>>>(zh, eidx, nidx, W1, b1, W2, b2, accum, E);
    fin_kernel<<<1, 1, 0, stream>>>(accum, (float*)d_out, nNodes, E);
}

// Round 6
// 213.618 us; speedup vs baseline: 1.1159x; 1.0335x over previous
//
#include <hip/hip_runtime.h>
#include <math.h>

#define F_DIM 128
#define D_LAT 64
#define H_DIM 128

typedef __attribute__((ext_vector_type(8))) short bf16x8;        // 8 bf16 (4 VGPRs)
typedef __attribute__((ext_vector_type(4))) float f32x4;
typedef __attribute__((ext_vector_type(2))) float f32x2;

__device__ __forceinline__ unsigned short f2bf(float f) {
    unsigned int u = __builtin_bit_cast(unsigned int, f);
    return (unsigned short)((u + 0x8000u) >> 16);
}

// 8 fp8 bytes (qu) x 8 fp8 bytes (qv) -> elementwise product as 8 fp8 bytes (i64)
__device__ __forceinline__ long prod_fp8(unsigned long long qu, unsigned long long qv) {
    const unsigned int ul = (unsigned int)qu, uh = (unsigned int)(qu >> 32);
    const unsigned int vl = (unsigned int)qv, vh = (unsigned int)(qv >> 32);
    const f32x2 u01 = __builtin_amdgcn_cvt_pk_f32_fp8(ul, false);
    const f32x2 u23 = __builtin_amdgcn_cvt_pk_f32_fp8(ul, true);
    const f32x2 u45 = __builtin_amdgcn_cvt_pk_f32_fp8(uh, false);
    const f32x2 u67 = __builtin_amdgcn_cvt_pk_f32_fp8(uh, true);
    const f32x2 v01 = __builtin_amdgcn_cvt_pk_f32_fp8(vl, false);
    const f32x2 v23 = __builtin_amdgcn_cvt_pk_f32_fp8(vl, true);
    const f32x2 v45 = __builtin_amdgcn_cvt_pk_f32_fp8(vh, false);
    const f32x2 v67 = __builtin_amdgcn_cvt_pk_f32_fp8(vh, true);
    const f32x2 p01 = u01 * v01, p23 = u23 * v23;
    const f32x2 p45 = u45 * v45, p67 = u67 * v67;
    unsigned int r0 = __builtin_amdgcn_cvt_pk_fp8_f32(p01[0], p01[1], 0u, false);
    r0 = __builtin_amdgcn_cvt_pk_fp8_f32(p23[0], p23[1], r0, true);
    unsigned int r1 = __builtin_amdgcn_cvt_pk_fp8_f32(p45[0], p45[1], 0u, false);
    r1 = __builtin_amdgcn_cvt_pk_fp8_f32(p67[0], p67[1], r1, true);
    return (long)(((unsigned long long)r1 << 32) | r0);
}

// ---------------- encoder via MFMA: 16 nodes/wave, z stored fp8 e4m3 ----------------
// mfma 16x16x32 layouts (m89-verified, validated by absmax 0.0 in R2-R5):
//   A: lane l, elem j -> A[l&15][(l>>4)*8 + j]
//   B: lane l, elem j -> B[(l>>4)*8 + j][l&15]
//   D: lane l, reg r  -> D[(l>>4)*4 + r][l&15]
__global__ __launch_bounds__(256) void enc_mfma_kernel(
    const float* __restrict__ x, const float* __restrict__ eps,
    const float* __restrict__ Wmu, const float* __restrict__ bmu,
    const float* __restrict__ Wlv, const float* __restrict__ blv,
    unsigned char* __restrict__ zb, float* __restrict__ accum, int nNodes)
{
    const int lane = threadIdx.x & 63;
    const int li   = lane & 15;
    const int gi   = lane >> 4;

    bf16x8 wf[8][4];
#pragma unroll
    for (int t = 0; t < 4; ++t)
#pragma unroll
        for (int s = 0; s < 4; ++s)
#pragma unroll
            for (int j = 0; j < 8; ++j) {
                const int k = s * 32 + gi * 8 + j;
                wf[t][s][j]     = (short)f2bf(Wmu[k * D_LAT + 16 * t + li]);
                wf[t + 4][s][j] = (short)f2bf(Wlv[k * D_LAT + 16 * t + li]);
            }
    float bmu4[4], blv4[4];
#pragma unroll
    for (int t = 0; t < 4; ++t) {
        bmu4[t] = bmu[16 * t + li];
        blv4[t] = blv[16 * t + li];
    }

    const int wid = (blockIdx.x * blockDim.x + threadIdx.x) >> 6;
    const int nw  = (gridDim.x * blockDim.x) >> 6;
    const int NB  = nNodes >> 4;

    float klacc = 0.f;
    for (int nb = wid; nb < NB; nb += nw) {
        const int nbase = nb << 4;
        const float* __restrict__ xrow = x + (size_t)(nbase + li) * F_DIM;

        bf16x8 af[4];
#pragma unroll
        for (int s = 0; s < 4; ++s) {
            const f32x4 v0 = *(const f32x4*)(xrow + s * 32 + gi * 8);
            const f32x4 v1 = *(const f32x4*)(xrow + s * 32 + gi * 8 + 4);
#pragma unroll
            for (int j = 0; j < 4; ++j) {
                af[s][j]     = (short)f2bf(v0[j]);
                af[s][j + 4] = (short)f2bf(v1[j]);
            }
        }

        f32x4 acc[8];
#pragma unroll
        for (int t = 0; t < 4; ++t) {
            acc[t]     = (f32x4){bmu4[t], bmu4[t], bmu4[t], bmu4[t]};
            acc[t + 4] = (f32x4){blv4[t], blv4[t], blv4[t], blv4[t]};
        }
#pragma unroll
        for (int t = 0; t < 8; ++t)
#pragma unroll
            for (int s = 0; s < 4; ++s)
                acc[t] = __builtin_amdgcn_mfma_f32_16x16x32_bf16(af[s], wf[t][s], acc[t], 0, 0, 0);

#pragma unroll
        for (int r = 0; r < 4; ++r) {
            const int row = nbase + gi * 4 + r;
#pragma unroll
            for (int t = 0; t < 4; ++t) {
                const float mu  = acc[t][r];
                const float lv  = acc[t + 4][r];
                const float e05 = __expf(0.5f * lv);
                klacc += mu * mu + e05 * e05 - 1.0f - lv;
                const float zv = fmaf(eps[(size_t)row * D_LAT + 16 * t + li], e05, mu);
                zb[(size_t)row * D_LAT + 16 * t + li] =
                    (unsigned char)(__builtin_amdgcn_cvt_pk_fp8_f32(zv, 0.f, 0u, false) & 0xffu);
            }
        }
    }
    for (int off = 32; off; off >>= 1) klacc += __shfl_xor(klacc, off);
    if (lane == 0) atomicAdd(&accum[1], 0.5f * klacc);
}

// ---------------- edge scorer: 32 pairs/wave/iter, fp8 rows (64B = 1 line) ----------------
__global__ __launch_bounds__(256) void edge_mfma_kernel(
    const unsigned char* __restrict__ zb,
    const int* __restrict__ eidx, const int* __restrict__ nidx,
    const float* __restrict__ W1, const float* __restrict__ b1,
    const float* __restrict__ W2, const float* __restrict__ b2,
    float* __restrict__ accum, int E)
{
    const int lane = threadIdx.x & 63;
    const int li   = lane & 15;
    const int gi   = lane >> 4;

    // W1 quantized to fp8 in registers: 16 x i64 = 32 VGPR
    long w1q[8][2];
#pragma unroll
    for (int t = 0; t < 8; ++t)
#pragma unroll
        for (int s = 0; s < 2; ++s) {
            float f[8];
#pragma unroll
            for (int j = 0; j < 8; ++j)
                f[j] = W1[(32 * s + gi * 8 + j) * H_DIM + 16 * t + li];
            unsigned int r0 = __builtin_amdgcn_cvt_pk_fp8_f32(f[0], f[1], 0u, false);
            r0 = __builtin_amdgcn_cvt_pk_fp8_f32(f[2], f[3], r0, true);
            unsigned int r1 = __builtin_amdgcn_cvt_pk_fp8_f32(f[4], f[5], 0u, false);
            r1 = __builtin_amdgcn_cvt_pk_fp8_f32(f[6], f[7], r1, true);
            w1q[t][s] = (long)(((unsigned long long)r1 << 32) | r0);
        }
    float b1r[8], w2r[8];
#pragma unroll
    for (int t = 0; t < 8; ++t) {
        b1r[t] = b1[16 * t + li];
        w2r[t] = W2[16 * t + li];
    }
    const float b2v = b2[0];

    const int wid = (blockIdx.x * blockDim.x + threadIdx.x) >> 6;
    const int nw  = (gridDim.x * blockDim.x) >> 6;
    const int NBpos = E >> 4;         // 62500
    const int NB    = NBpos << 1;     // 125000
    const int NBH   = NB >> 1;        // 62500 double-block iterations

    float lp = 0.f;

    int cu0, cv0, cu1, cv1;
    {
        const int hb  = (wid < NBH) ? wid : (NBH - 1);
        const int pb0 = 2 * hb, pb1 = 2 * hb + 1;
        const int* __restrict__ i0 = (pb0 < NBpos) ? eidx : nidx;
        const int* __restrict__ i1 = (pb1 < NBpos) ? eidx : nidx;
        const int m0 = ((pb0 < NBpos) ? pb0 : pb0 - NBpos) << 4;
        const int m1 = ((pb1 < NBpos) ? pb1 : pb1 - NBpos) << 4;
        cu0 = i0[m0 + li]; cv0 = i0[E + m0 + li];
        cu1 = i1[m1 + li]; cv1 = i1[E + m1 + li];
    }

    for (int hb = wid; hb < NBH; hb += nw) {
        const int pb0 = 2 * hb, pb1 = 2 * hb + 1;

        // --- 8 row-half gathers (8B each), 1 cache line per row ---
        const unsigned long long* zu0 = (const unsigned long long*)(zb + (size_t)cu0 * D_LAT + gi * 8);
        const unsigned long long* zv0 = (const unsigned long long*)(zb + (size_t)cv0 * D_LAT + gi * 8);
        const unsigned long long* zu1 = (const unsigned long long*)(zb + (size_t)cu1 * D_LAT + gi * 8);
        const unsigned long long* zv1 = (const unsigned long long*)(zb + (size_t)cv1 * D_LAT + gi * 8);
        const unsigned long long qu00 = zu0[0], qu01 = zu0[4];   // +32 bytes = 4 ulongs
        const unsigned long long qv00 = zv0[0], qv01 = zv0[4];
        const unsigned long long qu10 = zu1[0], qu11 = zu1[4];
        const unsigned long long qv10 = zv1[0], qv11 = zv1[4];

        // --- prefetch next indices ---
        int nu0, nv0, nu1, nv1;
        {
            const int hn  = (hb + nw < NBH) ? hb + nw : hb;
            const int qb0 = 2 * hn, qb1 = 2 * hn + 1;
            const int* __restrict__ i0 = (qb0 < NBpos) ? eidx : nidx;
            const int* __restrict__ i1 = (qb1 < NBpos) ? eidx : nidx;
            const int m0 = ((qb0 < NBpos) ? qb0 : qb0 - NBpos) << 4;
            const int m1 = ((qb1 < NBpos) ? qb1 : qb1 - NBpos) << 4;
            nu0 = i0[m0 + li]; nv0 = i0[E + m0 + li];
            nu1 = i1[m1 + li]; nv1 = i1[E + m1 + li];
        }

#pragma unroll
        for (int blk = 0; blk < 2; ++blk) {
            const long pa0 = prod_fp8(blk ? qu10 : qu00, blk ? qv10 : qv00);
            const long pa1 = prod_fp8(blk ? qu11 : qu01, blk ? qv11 : qv01);
            f32x4 acc[8];
#pragma unroll
            for (int t = 0; t < 8; ++t)
                acc[t] = (f32x4){b1r[t], b1r[t], b1r[t], b1r[t]};
#pragma unroll
            for (int t = 0; t < 8; ++t) {
                acc[t] = __builtin_amdgcn_mfma_f32_16x16x32_fp8_fp8(pa0, w1q[t][0], acc[t], 0, 0, 0);
                acc[t] = __builtin_amdgcn_mfma_f32_16x16x32_fp8_fp8(pa1, w1q[t][1], acc[t], 0, 0, 0);
            }
            float t0 = 0.f, t1 = 0.f, t2 = 0.f, t3 = 0.f;
#pragma unroll
            for (int t = 0; t < 8; ++t) {
                t0 += fmaxf(acc[t][0], 0.f) * w2r[t];
                t1 += fmaxf(acc[t][1], 0.f) * w2r[t];
                t2 += fmaxf(acc[t][2], 0.f) * w2r[t];
                t3 += fmaxf(acc[t][3], 0.f) * w2r[t];
            }
#pragma unroll
            for (int off = 1; off < 16; off <<= 1) {
                t0 += __shfl_xor(t0, off);
                t1 += __shfl_xor(t1, off);
                t2 += __shfl_xor(t2, off);
                t3 += __shfl_xor(t3, off);
            }
            const int pb = blk ? pb1 : pb0;
            const float sg = (pb < NBpos) ? 1.f : -1.f;
            const float l0 = sg * (t0 + b2v), l1 = sg * (t1 + b2v);
            const float l2 = sg * (t2 + b2v), l3 = sg * (t3 + b2v);
            lp += fminf(l0, 0.f) - __logf(1.f + __expf(-fabsf(l0)));
            lp += fminf(l1, 0.f) - __logf(1.f + __expf(-fabsf(l1)));
            lp += fminf(l2, 0.f) - __logf(1.f + __expf(-fabsf(l2)));
            lp += fminf(l3, 0.f) - __logf(1.f + __expf(-fabsf(l3)));
        }

        cu0 = nu0; cv0 = nv0; cu1 = nu1; cv1 = nv1;
    }
    for (int off = 32; off; off >>= 1) lp += __shfl_xor(lp, off);
    if (lane == 0) atomicAdd(&accum[0], lp * 0.0625f);
}

// ---------------- finalize ----------------
__global__ void fin_kernel(const float* __restrict__ accum, float* __restrict__ out,
                           int nNodes, int E)
{
    const float recon = accum[0] / (float)(2 * E);
    const float kl    = accum[1] / (float)nNodes;
    out[0] = kl - recon;
}

extern "C" void kernel_launch(void* const* d_in, const int* in_sizes, int n_in,
                              void* d_out, int out_size, void* d_ws, size_t ws_size,
                              hipStream_t stream)
{
    const float* x    = (const float*)d_in[0];
    const float* eps  = (const float*)d_in[1];
    const float* Wmu  = (const float*)d_in[2];
    const float* bmu  = (const float*)d_in[3];
    const float* Wlv  = (const float*)d_in[4];
    const float* blv  = (const float*)d_in[5];
    const float* W1   = (const float*)d_in[6];
    const float* b1   = (const float*)d_in[7];
    const float* W2   = (const float*)d_in[8];
    const float* b2   = (const float*)d_in[9];
    const int*   eidx = (const int*)d_in[10];
    const int*   nidx = (const int*)d_in[11];

    const int nNodes = in_sizes[1] / D_LAT;   // 100000
    const int E      = in_sizes[10] / 2;      // 1000000

    float* accum      = (float*)d_ws;
    unsigned char* zb = (unsigned char*)((char*)d_ws + 256);   // nNodes*64 fp8 bytes

    hipMemsetAsync(d_ws, 0, 256, stream);
    enc_mfma_kernel<<<512, 256, 0, stream>>>(x, eps, Wmu, bmu, Wlv, blv, zb, accum, nNodes);
    edge_mfma_kernel<<<2048, 256, 0, stream>>>(zb, eidx, nidx, W1, b1, W2, b2, accum, E);
    fin_kernel<<<1, 1, 0, stream>>>(accum, (float*)d_out, nNodes, E);
}

// Round 7
// 202.443 us; speedup vs baseline: 1.1775x; 1.0552x over previous
//
#include <hip/hip_runtime.h>
#include <math.h>

#define F_DIM 128
#define D_LAT 64
#define H_DIM 128

typedef __attribute__((ext_vector_type(8))) short bf16x8;        // 8 bf16 (4 VGPRs)
typedef __attribute__((ext_vector_type(4))) float f32x4;
typedef __attribute__((ext_vector_type(2))) float f32x2;
typedef __attribute__((ext_vector_type(2))) unsigned long long u64x2;

__device__ __forceinline__ unsigned short f2bf(float f) {
    unsigned int u = __builtin_bit_cast(unsigned int, f);
    return (unsigned short)((u + 0x8000u) >> 16);
}

// 8 fp8 bytes x 8 fp8 bytes -> elementwise product as 8 fp8 bytes (i64)
__device__ __forceinline__ long prod_fp8(unsigned long long qu, unsigned long long qv) {
    const unsigned int ul = (unsigned int)qu, uh = (unsigned int)(qu >> 32);
    const unsigned int vl = (unsigned int)qv, vh = (unsigned int)(qv >> 32);
    const f32x2 u01 = __builtin_amdgcn_cvt_pk_f32_fp8(ul, false);
    const f32x2 u23 = __builtin_amdgcn_cvt_pk_f32_fp8(ul, true);
    const f32x2 u45 = __builtin_amdgcn_cvt_pk_f32_fp8(uh, false);
    const f32x2 u67 = __builtin_amdgcn_cvt_pk_f32_fp8(uh, true);
    const f32x2 v01 = __builtin_amdgcn_cvt_pk_f32_fp8(vl, false);
    const f32x2 v23 = __builtin_amdgcn_cvt_pk_f32_fp8(vl, true);
    const f32x2 v45 = __builtin_amdgcn_cvt_pk_f32_fp8(vh, false);
    const f32x2 v67 = __builtin_amdgcn_cvt_pk_f32_fp8(vh, true);
    const f32x2 p01 = u01 * v01, p23 = u23 * v23;
    const f32x2 p45 = u45 * v45, p67 = u67 * v67;
    unsigned int r0 = __builtin_amdgcn_cvt_pk_fp8_f32(p01[0], p01[1], 0u, false);
    r0 = __builtin_amdgcn_cvt_pk_fp8_f32(p23[0], p23[1], r0, true);
    unsigned int r1 = __builtin_amdgcn_cvt_pk_fp8_f32(p45[0], p45[1], 0u, false);
    r1 = __builtin_amdgcn_cvt_pk_fp8_f32(p67[0], p67[1], r1, true);
    return (long)(((unsigned long long)r1 << 32) | r0);
}

// ---------------- encoder via MFMA: 16 nodes/wave, z stored fp8 e4m3 ----------------
// mfma 16x16x32 layouts (m89-verified, validated by absmax 0.0 in R2-R6):
//   A: lane l, elem j -> A[l&15][(l>>4)*8 + j]
//   B: lane l, elem j -> B[(l>>4)*8 + j][l&15]
//   D: lane l, reg r  -> D[(l>>4)*4 + r][l&15]
__global__ __launch_bounds__(256) void enc_mfma_kernel(
    const float* __restrict__ x, const float* __restrict__ eps,
    const float* __restrict__ Wmu, const float* __restrict__ bmu,
    const float* __restrict__ Wlv, const float* __restrict__ blv,
    unsigned char* __restrict__ zb, float* __restrict__ accum, int nNodes)
{
    const int lane = threadIdx.x & 63;
    const int li   = lane & 15;
    const int gi   = lane >> 4;

    bf16x8 wf[8][4];
#pragma unroll
    for (int t = 0; t < 4; ++t)
#pragma unroll
        for (int s = 0; s < 4; ++s)
#pragma unroll
            for (int j = 0; j < 8; ++j) {
                const int k = s * 32 + gi * 8 + j;
                wf[t][s][j]     = (short)f2bf(Wmu[k * D_LAT + 16 * t + li]);
                wf[t + 4][s][j] = (short)f2bf(Wlv[k * D_LAT + 16 * t + li]);
            }
    float bmu4[4], blv4[4];
#pragma unroll
    for (int t = 0; t < 4; ++t) {
        bmu4[t] = bmu[16 * t + li];
        blv4[t] = blv[16 * t + li];
    }

    const int wid = (blockIdx.x * blockDim.x + threadIdx.x) >> 6;
    const int nw  = (gridDim.x * blockDim.x) >> 6;
    const int NB  = nNodes >> 4;

    float klacc = 0.f;
    for (int nb = wid; nb < NB; nb += nw) {
        const int nbase = nb << 4;
        const float* __restrict__ xrow = x + (size_t)(nbase + li) * F_DIM;

        bf16x8 af[4];
#pragma unroll
        for (int s = 0; s < 4; ++s) {
            const f32x4 v0 = *(const f32x4*)(xrow + s * 32 + gi * 8);
            const f32x4 v1 = *(const f32x4*)(xrow + s * 32 + gi * 8 + 4);
#pragma unroll
            for (int j = 0; j < 4; ++j) {
                af[s][j]     = (short)f2bf(v0[j]);
                af[s][j + 4] = (short)f2bf(v1[j]);
            }
        }

        f32x4 acc[8];
#pragma unroll
        for (int t = 0; t < 4; ++t) {
            acc[t]     = (f32x4){bmu4[t], bmu4[t], bmu4[t], bmu4[t]};
            acc[t + 4] = (f32x4){blv4[t], blv4[t], blv4[t], blv4[t]};
        }
#pragma unroll
        for (int t = 0; t < 8; ++t)
#pragma unroll
            for (int s = 0; s < 4; ++s)
                acc[t] = __builtin_amdgcn_mfma_f32_16x16x32_bf16(af[s], wf[t][s], acc[t], 0, 0, 0);

#pragma unroll
        for (int r = 0; r < 4; ++r) {
            const int row = nbase + gi * 4 + r;
#pragma unroll
            for (int t = 0; t < 4; ++t) {
                const float mu  = acc[t][r];
                const float lv  = acc[t + 4][r];
                const float e05 = __expf(0.5f * lv);
                klacc += mu * mu + e05 * e05 - 1.0f - lv;
                const float zv = fmaf(eps[(size_t)row * D_LAT + 16 * t + li], e05, mu);
                zb[(size_t)row * D_LAT + 16 * t + li] =
                    (unsigned char)(__builtin_amdgcn_cvt_pk_fp8_f32(zv, 0.f, 0u, false) & 0xffu);
            }
        }
    }
    for (int off = 32; off; off >>= 1) klacc += __shfl_xor(klacc, off);
    if (lane == 0) atomicAdd(&accum[1], 0.5f * klacc);
}

// ---------------- edge scorer: software-pipelined gathers, dwordx4 rows ----------------
// k-dimension permuted consistently on A and B: frag s, lane gi, elem j <-> k = gi*16 + s*8 + j
__global__ __launch_bounds__(256) void edge_mfma_kernel(
    const unsigned char* __restrict__ zb,
    const int* __restrict__ eidx, const int* __restrict__ nidx,
    const float* __restrict__ W1, const float* __restrict__ b1,
    const float* __restrict__ W2, const float* __restrict__ b2,
    float* __restrict__ accum, int E)
{
    const int lane = threadIdx.x & 63;
    const int li   = lane & 15;
    const int gi   = lane >> 4;

    // W1 quantized to fp8 in registers (permuted-k mapping): 16 x i64 = 32 VGPR
    long w1q[8][2];
#pragma unroll
    for (int t = 0; t < 8; ++t)
#pragma unroll
        for (int s = 0; s < 2; ++s) {
            float f[8];
#pragma unroll
            for (int j = 0; j < 8; ++j)
                f[j] = W1[(gi * 16 + s * 8 + j) * H_DIM + 16 * t + li];
            unsigned int r0 = __builtin_amdgcn_cvt_pk_fp8_f32(f[0], f[1], 0u, false);
            r0 = __builtin_amdgcn_cvt_pk_fp8_f32(f[2], f[3], r0, true);
            unsigned int r1 = __builtin_amdgcn_cvt_pk_fp8_f32(f[4], f[5], 0u, false);
            r1 = __builtin_amdgcn_cvt_pk_fp8_f32(f[6], f[7], r1, true);
            w1q[t][s] = (long)(((unsigned long long)r1 << 32) | r0);
        }
    float b1r[8], w2r[8];
#pragma unroll
    for (int t = 0; t < 8; ++t) {
        b1r[t] = b1[16 * t + li];
        w2r[t] = W2[16 * t + li];
    }
    const float b2v = b2[0];

    const int wid = (blockIdx.x * blockDim.x + threadIdx.x) >> 6;
    const int nw  = (gridDim.x * blockDim.x) >> 6;
    const int NBpos = E >> 4;        // 62500 positive blocks
    const int NBH   = NBpos;         // iterations of 2 blocks (2*NBpos total blocks)

    float lp = 0.f;

    auto load_idx = [&](int hb, int& u0, int& v0, int& u1, int& v1) {
        const int h   = (hb < NBH) ? hb : (NBH - 1);
        const int pb0 = 2 * h, pb1 = 2 * h + 1;
        const int* __restrict__ i0 = (pb0 < NBpos) ? eidx : nidx;
        const int* __restrict__ i1 = (pb1 < NBpos) ? eidx : nidx;
        const int m0 = ((pb0 < NBpos) ? pb0 : pb0 - NBpos) << 4;
        const int m1 = ((pb1 < NBpos) ? pb1 : pb1 - NBpos) << 4;
        u0 = i0[m0 + li]; v0 = i0[E + m0 + li];
        u1 = i1[m1 + li]; v1 = i1[E + m1 + li];
    };
    auto load_row = [&](int node) -> u64x2 {
        return *(const u64x2*)(zb + (size_t)node * D_LAT + (gi << 4));
    };
    auto do_block = [&](u64x2 qu, u64x2 qv, bool pos) {
        const long pa0 = prod_fp8(qu[0], qv[0]);
        const long pa1 = prod_fp8(qu[1], qv[1]);
        f32x4 acc[8];
#pragma unroll
        for (int t = 0; t < 8; ++t)
            acc[t] = (f32x4){b1r[t], b1r[t], b1r[t], b1r[t]};
#pragma unroll
        for (int t = 0; t < 8; ++t) {
            acc[t] = __builtin_amdgcn_mfma_f32_16x16x32_fp8_fp8(pa0, w1q[t][0], acc[t], 0, 0, 0);
            acc[t] = __builtin_amdgcn_mfma_f32_16x16x32_fp8_fp8(pa1, w1q[t][1], acc[t], 0, 0, 0);
        }
        float t0 = 0.f, t1 = 0.f, t2 = 0.f, t3 = 0.f;
#pragma unroll
        for (int t = 0; t < 8; ++t) {
            t0 += fmaxf(acc[t][0], 0.f) * w2r[t];
            t1 += fmaxf(acc[t][1], 0.f) * w2r[t];
            t2 += fmaxf(acc[t][2], 0.f) * w2r[t];
            t3 += fmaxf(acc[t][3], 0.f) * w2r[t];
        }
#pragma unroll
        for (int off = 1; off < 16; off <<= 1) {
            t0 += __shfl_xor(t0, off);
            t1 += __shfl_xor(t1, off);
            t2 += __shfl_xor(t2, off);
            t3 += __shfl_xor(t3, off);
        }
        const float sg = pos ? 1.f : -1.f;
        const float l0 = sg * (t0 + b2v), l1 = sg * (t1 + b2v);
        const float l2 = sg * (t2 + b2v), l3 = sg * (t3 + b2v);
        lp += fminf(l0, 0.f) - __logf(1.f + __expf(-fabsf(l0)));
        lp += fminf(l1, 0.f) - __logf(1.f + __expf(-fabsf(l1)));
        lp += fminf(l2, 0.f) - __logf(1.f + __expf(-fabsf(l2)));
        lp += fminf(l3, 0.f) - __logf(1.f + __expf(-fabsf(l3)));
    };

    // ---- pipeline prologue ----
    // idx for first iter (wid), then data(wid) and idx(wid+nw) in flight
    int ju0, jv0, ju1, jv1;       // idx for iteration whose DATA is being loaded
    load_idx(wid, ju0, jv0, ju1, jv1);
    u64x2 A0u = load_row(ju0), A0v = load_row(jv0);
    u64x2 A1u = load_row(ju1), A1v = load_row(jv1);
    load_idx(wid + nw, ju0, jv0, ju1, jv1);

#pragma unroll 2
    for (int hb = wid; hb < NBH; hb += nw) {
        // stage 1: issue data loads for hb+nw (idx already resident)
        u64x2 B0u = load_row(ju0), B0v = load_row(jv0);
        u64x2 B1u = load_row(ju1), B1v = load_row(jv1);
        // stage 0: issue idx loads for hb+2nw
        int ku0, kv0, ku1, kv1;
        load_idx(hb + 2 * nw, ku0, kv0, ku1, kv1);
        // stage 2: compute current (data already arriving)
        do_block(A0u, A0v, 2 * hb < NBpos);
        do_block(A1u, A1v, 2 * hb + 1 < NBpos);
        // rotate
        A0u = B0u; A0v = B0v; A1u = B1u; A1v = B1v;
        ju0 = ku0; jv0 = kv0; ju1 = ku1; jv1 = kv1;
    }

    for (int off = 32; off; off >>= 1) lp += __shfl_xor(lp, off);
    if (lane == 0) atomicAdd(&accum[0], lp * 0.0625f);
}

// ---------------- finalize ----------------
__global__ void fin_kernel(const float* __restrict__ accum, float* __restrict__ out,
                           int nNodes, int E)
{
    const float recon = accum[0] / (float)(2 * E);
    const float kl    = accum[1] / (float)nNodes;
    out[0] = kl - recon;
}

extern "C" void kernel_launch(void* const* d_in, const int* in_sizes, int n_in,
                              void* d_out, int out_size, void* d_ws, size_t ws_size,
                              hipStream_t stream)
{
    const float* x    = (const float*)d_in[0];
    const float* eps  = (const float*)d_in[1];
    const float* Wmu  = (const float*)d_in[2];
    const float* bmu  = (const float*)d_in[3];
    const float* Wlv  = (const float*)d_in[4];
    const float* blv  = (const float*)d_in[5];
    const float* W1   = (const float*)d_in[6];
    const float* b1   = (const float*)d_in[7];
    const float* W2   = (const float*)d_in[8];
    const float* b2   = (const float*)d_in[9];
    const int*   eidx = (const int*)d_in[10];
    const int*   nidx = (const int*)d_in[11];

    const int nNodes = in_sizes[1] / D_LAT;   // 100000
    const int E      = in_sizes[10] / 2;      // 1000000

    float* accum      = (float*)d_ws;
    unsigned char* zb = (unsigned char*)((char*)d_ws + 256);   // nNodes*64 fp8 bytes

    hipMemsetAsync(d_ws, 0, 256, stream);
    enc_mfma_kernel<<<512, 256, 0, stream>>>(x, eps, Wmu, bmu, Wlv, blv, zb, accum, nNodes);
    edge_mfma_kernel<<<2048, 256, 0, stream>>>(zb, eidx, nidx, W1, b1, W2, b2, accum, E);
    fin_kernel<<<1, 1, 0, stream>>>(accum, (float*)d_out, nNodes, E);
}